// Round 15
// baseline (291.020 us; speedup 1.0000x reference)
//
#include <hip/hip_runtime.h>
#include <hip/hip_bf16.h>

typedef __attribute__((ext_vector_type(8))) short short8;
typedef __attribute__((ext_vector_type(4))) float f32x4;
typedef __attribute__((ext_vector_type(4))) unsigned short u16x4;

// B=8 S=512 H=1024 NH=16 D=64 FF=4096 ; tokens M=4096

__device__ __forceinline__ unsigned short f2bf(float f){
  union { float f; unsigned u; } v; v.f = f;
  return (unsigned short)((v.u + 0x7FFFu + ((v.u >> 16) & 1u)) >> 16);
}
__device__ __forceinline__ float bf2f(unsigned short h){
  union { unsigned u; float f; } v; v.u = ((unsigned)h) << 16; return v.f;
}
// async global->LDS, 16B per lane; lds base must be wave-uniform (HW: base + lane*16)
__device__ __forceinline__ void gll16(const unsigned short* g, unsigned short* l){
  __builtin_amdgcn_global_load_lds((const __attribute__((address_space(1))) unsigned int*)g,
                                   (__attribute__((address_space(3))) unsigned int*)l, 16, 0, 0);
}

// ---------------- prep kernels ----------------
__global__ __launch_bounds__(256) void cast_x_kernel(const float* __restrict__ x,
                                                     unsigned short* __restrict__ xb){
  size_t i = (size_t)blockIdx.x * 256 + threadIdx.x;
  const f32x4 v = *(const f32x4*)(x + i * 4);
  u16x4 o;
  o[0] = f2bf(v[0]); o[1] = f2bf(v[1]); o[2] = f2bf(v[2]); o[3] = f2bf(v[3]);
  *(u16x4*)(xb + i * 4) = o;
}

// src fp32 [R][C] -> dst bf16 [C][R]
__global__ __launch_bounds__(256) void transpose_cast(const float* __restrict__ src,
                                                      unsigned short* __restrict__ dst,
                                                      int R, int C){
  __shared__ float tile[32][33];
  const int tx = threadIdx.x, ty = threadIdx.y;
  const int c0 = blockIdx.x * 32, r0 = blockIdx.y * 32;
  #pragma unroll
  for (int i = ty; i < 32; i += 8)
    tile[i][tx] = src[(size_t)(r0 + i) * C + c0 + tx];
  __syncthreads();
  #pragma unroll
  for (int i = ty; i < 32; i += 8)
    dst[(size_t)(c0 + i) * R + r0 + tx] = f2bf(tile[tx][i]);
}

__global__ void pack_bias3(const float* __restrict__ a, const float* __restrict__ b,
                           const float* __restrict__ c, float* __restrict__ out){
  const int i = blockIdx.x * 256 + threadIdx.x;
  out[i] = (i < 1024) ? a[i] : (i < 2048 ? b[i - 1024] : c[i - 2048]);
}

// ======== gemm1b: 128x128 tile, 4 waves, BK=64 SINGLE buffer, 32KB LDS ========
// SESSION-BEST GEMM (R10-R14 verified): ~675 TF, VGPR 80, 0 bank conflicts, 4 blocks/CU.
// Deployed: QKV / oproj / FF2 (controls this round).
// EPI: 0 = bias->bf16 ; 1 = bias+gelu->bf16 ; 3 = raw->bf16 partial (split-K, no bias)
template<int EPI>
__global__ __launch_bounds__(256) void gemm1b(const unsigned short* __restrict__ A,
                                              const unsigned short* __restrict__ Bt,
                                              const float* __restrict__ bias,
                                              unsigned short* __restrict__ Cout,
                                              int M, int N, int K, int Ksub){
  __shared__ unsigned short smA[128 * 64];
  __shared__ unsigned short smB[128 * 64];
  const int t = threadIdx.x;
  const int lane = t & 63, w = t >> 6;
  const int wr = w >> 1, wc = w & 1;
  const int g = lane >> 4, c = lane & 15;

  // bijective XCD swizzle (m204 form)
  const int gx = gridDim.x;
  const int nwg = gx * gridDim.y;
  int lin = blockIdx.y * gx + blockIdx.x;
  { const int q = nwg >> 3, r = nwg & 7, x = lin & 7, p = lin >> 3;
    lin = (x < r) ? x * (q + 1) + p : r * (q + 1) + (x - r) * q + p; }
  const int bn = lin % gx, bm = lin / gx;

  const size_t Kd = (size_t)K;
  const int k0 = blockIdx.z * Ksub;

  const int srow = t >> 3;                   // 0..31
  const int sslot = (t & 7) ^ (srow & 7);    // inverse-swizzled global slot
  const unsigned short* gA = A + (size_t)(bm * 128 + srow) * Kd + k0 + sslot * 8;
  const unsigned short* gB = Bt + (size_t)(bn * 128 + srow) * Kd + k0 + sslot * 8;

  const int arow = (wr * 64 + c) * 64;
  const int brow = (wc * 64 + c) * 64;
  const int sl0 = (g ^ (c & 7)) * 8;
  const int sl1 = ((g | 4) ^ (c & 7)) * 8;

  f32x4 acc[4][4];
  #pragma unroll
  for (int m = 0; m < 4; m++)
    #pragma unroll
    for (int n = 0; n < 4; n++) acc[m][n] = (f32x4){0.f, 0.f, 0.f, 0.f};
  short8 af[4], bfr[4];

  const int NT = Ksub >> 6;   // K-tiles of 64

#define STAGE1(T) do { \
    const unsigned short* ga_ = gA + (size_t)(T) * 64; \
    const unsigned short* gb_ = gB + (size_t)(T) * 64; \
    gll16(ga_,            &smA[(0  + w * 8) * 64]); \
    gll16(ga_ + 32 * Kd,  &smA[(32 + w * 8) * 64]); \
    gll16(ga_ + 64 * Kd,  &smA[(64 + w * 8) * 64]); \
    gll16(ga_ + 96 * Kd,  &smA[(96 + w * 8) * 64]); \
    gll16(gb_,            &smB[(0  + w * 8) * 64]); \
    gll16(gb_ + 32 * Kd,  &smB[(32 + w * 8) * 64]); \
    gll16(gb_ + 64 * Kd,  &smB[(64 + w * 8) * 64]); \
    gll16(gb_ + 96 * Kd,  &smB[(96 + w * 8) * 64]); } while (0)

  for (int tt = 0; tt < NT; ++tt){
    if (tt) __builtin_amdgcn_s_barrier();     // all waves done reading previous tile
    STAGE1(tt);
    asm volatile("s_waitcnt vmcnt(0)" ::: "memory");
    __builtin_amdgcn_s_barrier();             // tile visible to all waves
    #pragma unroll
    for (int m = 0; m < 4; m++) af[m]  = *(const short8*)&smA[arow + m * 1024 + sl0];
    #pragma unroll
    for (int n = 0; n < 4; n++) bfr[n] = *(const short8*)&smB[brow + n * 1024 + sl0];
    __builtin_amdgcn_s_setprio(1);
    #pragma unroll
    for (int m = 0; m < 4; m++)
      #pragma unroll
      for (int n = 0; n < 4; n++)
        acc[m][n] = __builtin_amdgcn_mfma_f32_16x16x32_bf16(af[m], bfr[n], acc[m][n], 0, 0, 0);
    #pragma unroll
    for (int m = 0; m < 4; m++) af[m]  = *(const short8*)&smA[arow + m * 1024 + sl1];
    #pragma unroll
    for (int n = 0; n < 4; n++) bfr[n] = *(const short8*)&smB[brow + n * 1024 + sl1];
    #pragma unroll
    for (int m = 0; m < 4; m++)
      #pragma unroll
      for (int n = 0; n < 4; n++)
        acc[m][n] = __builtin_amdgcn_mfma_f32_16x16x32_bf16(af[m], bfr[n], acc[m][n], 0, 0, 0);
    __builtin_amdgcn_s_setprio(0);
  }
#undef STAGE1

  // epilogue: C[row0+m*16+4g+r][col0+n*16+c]
  const int row0 = bm * 128 + wr * 64;
  const int col0 = bn * 128 + wc * 64;
  unsigned short* outp = Cout + (EPI == 3 ? (size_t)blockIdx.z * ((size_t)M * N) : 0);
  #pragma unroll
  for (int n = 0; n < 4; n++){
    const int col = col0 + n * 16 + c;
    const float bs = (EPI == 3) ? 0.f : bias[col];
    #pragma unroll
    for (int m = 0; m < 4; m++){
      const int row = row0 + m * 16 + g * 4;
      #pragma unroll
      for (int r = 0; r < 4; r++){
        float v = acc[m][n][r] + bs;
        if (EPI == 1){
          // gelu(x) = x * sigmoid(2*sqrt(2/pi)*(x + 0.044715 x^3))  (== tanh form)
          const float u2 = 1.5957691216057308f * (v + 0.044715f * v * v * v);
          v = v * __fdividef(1.f, 1.f + __expf(-u2));
        }
        outp[(size_t)(row + r) * N + col] = f2bf(v);
      }
    }
  }
}

// ======== gemm8w: 256x256 8-wave rolling schedule + amdgpu_num_vgpr(256) ========
// FINAL EXPERIMENT (FF1): R2's correctness-verified kernel (passed on HW, 0 bank
// conflicts, counted vmcnt(4) rolling schedule) — its only defect was the allocator's
// 128-VGPR cap (spill: 220MB scratch). Three hint-style attributes failed; this uses the
// DIRECT override amdgpu_num_vgpr(256). m201 (1563 TF, 512thr, ~230 VGPR) proves the
// config is valid on gfx950. Falsifier: VGPR_Count==128 + WRITE_SIZE~250MB -> attribute
// refused, question closed, consolidate at 241.7us next round.
// Schedule per J (2 K-tiles, bufs 0/1): p1:A1h0(O) p2:A1h1(O) p3:B0h0(E+2)
// p4:B0h1(E+2)+vmcnt(4) p5:A0h0(E+2) p6:A0h1(E+2) p7:B1h0(O+2) p8:B1h1(O+2)+vmcnt(4).
// Last J peeled: stages p1/p2 only, vmcnt(0) at p4.
template<int EPI>
__global__ __attribute__((amdgpu_flat_work_group_size(512, 512), amdgpu_num_vgpr(256)))
void gemm8w(const unsigned short* __restrict__ A,
            const unsigned short* __restrict__ Bt,
            const float* __restrict__ bias,
            unsigned short* __restrict__ Cout,
            int M, int N, int K, int Ksub){
  __shared__ unsigned short smA[2][256 * 64];
  __shared__ unsigned short smB[2][256 * 64];
  const int t = threadIdx.x;
  const int lane = t & 63, w = t >> 6;
  const int wr = w >> 2, wc = w & 3;
  const int g = lane >> 4, c = lane & 15;

  // bijective XCD swizzle (m204 form)
  const int gx = gridDim.x;
  const int nwg = gx * gridDim.y;
  int lin = blockIdx.y * gx + blockIdx.x;
  { const int q = nwg >> 3, r = nwg & 7, x = lin & 7, p = lin >> 3;
    lin = (x < r) ? x * (q + 1) + p : r * (q + 1) + (x - r) * q + p; }
  const int bn = lin % gx, bm = lin / gx;

  const size_t Kd = (size_t)K;
  const int k0 = blockIdx.z * Ksub;

  const int srow = t >> 3;
  const int sslot = (t & 7) ^ (srow & 7);
  const unsigned short* gA = A + (size_t)(bm * 256 + srow) * Kd + k0 + sslot * 8;
  const unsigned short* gB = Bt + (size_t)(bn * 256 + srow) * Kd + k0 + sslot * 8;

  const int arow = (wr * 128 + c) * 64;
  const int brow = (wc * 64 + c) * 64;
  const int sl0 = (g ^ (c & 7)) * 8;
  const int sl1 = ((g | 4) ^ (c & 7)) * 8;

  f32x4 acc[8][4];
  #pragma unroll
  for (int m = 0; m < 8; m++)
    #pragma unroll
    for (int n = 0; n < 4; n++) acc[m][n] = (f32x4){0.f, 0.f, 0.f, 0.f};
  short8 af[4];
  short8 bf[2][4];

  const int NT = Ksub >> 6;
  const int NJ = NT >> 1;     // requires NJ >= 2

#define STAGE_A(BUF, H, T) do { \
    const unsigned short* gp_ = gA + (size_t)(H) * 128 * Kd + (size_t)(T) * 64; \
    gll16(gp_,            &smA[BUF][(H) * 8192 + w * 512]); \
    gll16(gp_ + 64 * Kd,  &smA[BUF][(H) * 8192 + 4096 + w * 512]); } while (0)
#define STAGE_B(BUF, H, T) do { \
    const unsigned short* gp_ = gB + (size_t)(H) * 128 * Kd + (size_t)(T) * 64; \
    gll16(gp_,            &smB[BUF][(H) * 8192 + w * 512]); \
    gll16(gp_ + 64 * Kd,  &smB[BUF][(H) * 8192 + 4096 + w * 512]); } while (0)
#define VM4 asm volatile("s_waitcnt vmcnt(4)" ::: "memory")
#define VM0 asm volatile("s_waitcnt vmcnt(0)" ::: "memory")
#define BAR __builtin_amdgcn_s_barrier()
#define NOP_ ((void)0)
#define PH(SB, MH, KS, RDB, STG, VM, EB) do { \
    if (RDB) { \
      _Pragma("unroll") \
      for (int n_ = 0; n_ < 4; n_++) \
        bf[KS][n_] = *(const short8*)&smB[SB][brow + n_ * 1024 + ((KS) ? sl1 : sl0)]; \
    } \
    _Pragma("unroll") \
    for (int m_ = 0; m_ < 4; m_++) \
      af[m_] = *(const short8*)&smA[SB][arow + ((MH) * 64 + m_ * 16) * 64 + ((KS) ? sl1 : sl0)]; \
    STG; \
    __builtin_amdgcn_s_barrier(); \
    asm volatile("s_waitcnt lgkmcnt(0)" ::: "memory"); \
    __builtin_amdgcn_s_setprio(1); \
    _Pragma("unroll") \
    for (int m_ = 0; m_ < 4; m_++) { \
      _Pragma("unroll") \
      for (int n_ = 0; n_ < 4; n_++) \
        acc[(MH) * 4 + m_][n_] = __builtin_amdgcn_mfma_f32_16x16x32_bf16( \
            af[m_], bf[KS][n_], acc[(MH) * 4 + m_][n_], 0, 0, 0); \
    } \
    __builtin_amdgcn_s_setprio(0); \
    VM; \
    EB; \
  } while (0)

  // prologue: tile0 fully + tile1 B-halves (queue shape == steady state)
  STAGE_B(0, 0, 0); STAGE_B(0, 1, 0);
  STAGE_A(0, 0, 0); STAGE_A(0, 1, 0);
  STAGE_B(1, 0, 1); STAGE_B(1, 1, 1);
  VM4;
  BAR;

  for (int J = 0; J < NJ; ++J){
    const int tO = 2 * J + 1, tE2 = 2 * J + 2, tO2 = 2 * J + 3;
    if (J < NJ - 1){
      PH(0, 0, 0, 1, STAGE_A(1, 0, tO),  NOP_, BAR);
      PH(0, 0, 1, 1, STAGE_A(1, 1, tO),  NOP_, BAR);
      PH(0, 1, 0, 0, STAGE_B(0, 0, tE2), NOP_, BAR);
      PH(0, 1, 1, 0, STAGE_B(0, 1, tE2), VM4,  BAR);
      PH(1, 0, 0, 1, STAGE_A(0, 0, tE2), NOP_, BAR);
      PH(1, 0, 1, 1, STAGE_A(0, 1, tE2), NOP_, BAR);
      PH(1, 1, 0, 0, STAGE_B(1, 0, tO2), NOP_, BAR);
      PH(1, 1, 1, 0, STAGE_B(1, 1, tO2), VM4,  BAR);
    } else {
      PH(0, 0, 0, 1, STAGE_A(1, 0, tO),  NOP_, BAR);
      PH(0, 0, 1, 1, STAGE_A(1, 1, tO),  NOP_, BAR);
      PH(0, 1, 0, 0, NOP_,               NOP_, BAR);
      PH(0, 1, 1, 0, NOP_,               VM0,  BAR);
      PH(1, 0, 0, 1, NOP_,               NOP_, BAR);
      PH(1, 0, 1, 1, NOP_,               NOP_, BAR);
      PH(1, 1, 0, 0, NOP_,               NOP_, BAR);
      PH(1, 1, 1, 0, NOP_,               NOP_, NOP_);
    }
  }

#undef PH
#undef STAGE_A
#undef STAGE_B
#undef VM4
#undef VM0
#undef BAR
#undef NOP_

  // epilogue: C[row0+m*16+4g+r][col0+n*16+c]
  const int row0 = bm * 256 + wr * 128;
  const int col0 = bn * 256 + wc * 64;
  unsigned short* outp = Cout + (EPI == 3 ? (size_t)blockIdx.z * ((size_t)M * N) : 0);
  #pragma unroll
  for (int n = 0; n < 4; n++){
    const int col = col0 + n * 16 + c;
    const float bs = (EPI == 3) ? 0.f : bias[col];
    #pragma unroll
    for (int m = 0; m < 8; m++){
      const int row = row0 + m * 16 + g * 4;
      #pragma unroll
      for (int r = 0; r < 4; r++){
        float v = acc[m][n][r] + bs;
        if (EPI == 1){
          const float u2 = 1.5957691216057308f * (v + 0.044715f * v * v * v);
          v = v * __fdividef(1.f, 1.f + __expf(-u2));
        }
        outp[(size_t)(row + r) * N + col] = f2bf(v);
      }
    }
  }
}

// ---------------- fused attention (R8: 2 blocks/CU via chunked K/V staging) ----------------
__global__ __launch_bounds__(256) void attn_kernel(const unsigned short* __restrict__ qkv,
                                                   const int* __restrict__ mask,
                                                   unsigned short* __restrict__ ctx){
  __shared__ unsigned short k_sm[256 * 72];    // [key-chunk][d], pad 64->72
  __shared__ unsigned short vt_sm[64 * 272];   // [d][key-chunk], pad 256->272
  __shared__ float madd[512];
  const int t = threadIdx.x;
  const int hb = blockIdx.x;
  const int qt = blockIdx.y;                   // 0..7
  const int b = hb >> 4, h = hb & 15;
  const size_t headq = (size_t)b * 512 * 3072 + h * 64;

#define STAGE_K(K0) do { \
    _Pragma("unroll") \
    for (int p = 0; p < 8; p++){ \
      const int row = p * 32 + (t >> 3); \
      const int col = (t & 7) * 8; \
      const short8 v = *(const short8*)(qkv + headq + (size_t)((K0) + row) * 3072 + 1024 + col); \
      *(short8*)(k_sm + row * 72 + col) = v; \
    } } while (0)
#define STAGE_VT(K0) do { \
    const unsigned short* vp_ = qkv + headq + (size_t)((K0) + t) * 3072 + 2048; \
    short8 vv_[8]; \
    _Pragma("unroll") \
    for (int j = 0; j < 8; j++) vv_[j] = *(const short8*)(vp_ + j * 8); \
    _Pragma("unroll") \
    for (int j = 0; j < 8; j++) \
      _Pragma("unroll") \
      for (int e = 0; e < 8; e++) \
        vt_sm[(j * 8 + e) * 272 + t] = (unsigned short)vv_[j][e]; \
  } while (0)

  STAGE_K(0);
  STAGE_VT(0);
  madd[t]       = (1.f - (float)mask[b * 512 + t]) * -10000.f;
  madd[256 + t] = (1.f - (float)mask[b * 512 + 256 + t]) * -10000.f;
  __syncthreads();

  const int w = t >> 6, lane = t & 63, g = lane >> 4, c = lane & 15;
  const int qrow = qt * 64 + w * 16 + c;
  const unsigned short* qp = qkv + (size_t)(b * 512 + qrow) * 3072 + h * 64;
  const short8 qf0 = *(const short8*)(qp + 8 * g);
  const short8 qf1 = *(const short8*)(qp + 32 + 8 * g);

  f32x4 p[32];
  // QK^T chunk 0 (keys 0..255)
  #pragma unroll
  for (int mt = 0; mt < 16; mt++){
    const short8 a0 = *(const short8*)(k_sm + (mt * 16 + c) * 72 + 8 * g);
    const short8 a1 = *(const short8*)(k_sm + (mt * 16 + c) * 72 + 32 + 8 * g);
    f32x4 z = (f32x4){0.f, 0.f, 0.f, 0.f};
    z = __builtin_amdgcn_mfma_f32_16x16x32_bf16(a0, qf0, z, 0, 0, 0);
    z = __builtin_amdgcn_mfma_f32_16x16x32_bf16(a1, qf1, z, 0, 0, 0);
    p[mt] = z;
  }
  __syncthreads();           // all waves done reading k_sm chunk 0
  STAGE_K(256);
  __syncthreads();
  // QK^T chunk 1 (keys 256..511)
  #pragma unroll
  for (int mt = 16; mt < 32; mt++){
    const short8 a0 = *(const short8*)(k_sm + ((mt - 16) * 16 + c) * 72 + 8 * g);
    const short8 a1 = *(const short8*)(k_sm + ((mt - 16) * 16 + c) * 72 + 32 + 8 * g);
    f32x4 z = (f32x4){0.f, 0.f, 0.f, 0.f};
    z = __builtin_amdgcn_mfma_f32_16x16x32_bf16(a0, qf0, z, 0, 0, 0);
    z = __builtin_amdgcn_mfma_f32_16x16x32_bf16(a1, qf1, z, 0, 0, 0);
    p[mt] = z;
  }

  float mx = -1e30f;
  #pragma unroll
  for (int mt = 0; mt < 32; mt++){
    #pragma unroll
    for (int r = 0; r < 4; r++){
      const float sv = p[mt][r] * 0.125f + madd[mt * 16 + 4 * g + r];
      p[mt][r] = sv;
      mx = fmaxf(mx, sv);
    }
  }
  mx = fmaxf(mx, __shfl_xor(mx, 16));
  mx = fmaxf(mx, __shfl_xor(mx, 32));

  float sum = 0.f;
  unsigned pd[32][2];
  #pragma unroll
  for (int mt = 0; mt < 32; mt++){
    const float e0 = __expf(p[mt][0] - mx);
    const float e1 = __expf(p[mt][1] - mx);
    const float e2 = __expf(p[mt][2] - mx);
    const float e3 = __expf(p[mt][3] - mx);
    sum += (e0 + e1) + (e2 + e3);
    pd[mt][0] = (unsigned)f2bf(e0) | ((unsigned)f2bf(e1) << 16);
    pd[mt][1] = (unsigned)f2bf(e2) | ((unsigned)f2bf(e3) << 16);
  }
  sum += __shfl_xor(sum, 16);
  sum += __shfl_xor(sum, 32);
  const float rsum = 1.f / sum;

  f32x4 o[4];
  #pragma unroll
  for (int dt = 0; dt < 4; dt++) o[dt] = (f32x4){0.f, 0.f, 0.f, 0.f};
  const int sA = (2 * (g & 1)) * 16 + c;
  const int sB = sA + 16;
  const int hi = g >> 1;

#define PVBLK(KT0) \
  _Pragma("unroll") \
  for (int kk = 0; kk < 8; kk++){ \
    const int kt = (KT0) + kk; \
    const unsigned w0a = (unsigned)__shfl((int)pd[2 * kt][0], sA); \
    const unsigned w1a = (unsigned)__shfl((int)pd[2 * kt][1], sA); \
    const unsigned w2a = (unsigned)__shfl((int)pd[2 * kt][0], sB); \
    const unsigned w3a = (unsigned)__shfl((int)pd[2 * kt][1], sB); \
    const unsigned w0b = (unsigned)__shfl((int)pd[2 * kt + 1][0], sA); \
    const unsigned w1b = (unsigned)__shfl((int)pd[2 * kt + 1][1], sA); \
    const unsigned w2b = (unsigned)__shfl((int)pd[2 * kt + 1][0], sB); \
    const unsigned w3b = (unsigned)__shfl((int)pd[2 * kt + 1][1], sB); \
    union { unsigned u[4]; short8 s; } bu; \
    bu.u[0] = hi ? w0b : w0a; \
    bu.u[1] = hi ? w1b : w1a; \
    bu.u[2] = hi ? w2b : w2a; \
    bu.u[3] = hi ? w3b : w3a; \
    _Pragma("unroll") \
    for (int dt = 0; dt < 4; dt++){ \
      const short8 av = *(const short8*)(vt_sm + (dt * 16 + c) * 272 + kk * 32 + 8 * g); \
      o[dt] = __builtin_amdgcn_mfma_f32_16x16x32_bf16(av, bu.s, o[dt], 0, 0, 0); \
    } \
  }

  PVBLK(0);                  // keys 0..255 from vt chunk 0
  __syncthreads();           // all waves done reading vt chunk 0
  STAGE_VT(256);
  __syncthreads();
  PVBLK(8);                  // keys 256..511 from vt chunk 1

#undef PVBLK
#undef STAGE_K
#undef STAGE_VT

  #pragma unroll
  for (int dt = 0; dt < 4; dt++){
    u16x4 st;
    #pragma unroll
    for (int r = 0; r < 4; r++) st[r] = f2bf(o[dt][r] * rsum);
    *(u16x4*)(ctx + (size_t)(b * 512 + qrow) * 1024 + h * 64 + dt * 16 + 4 * g) = st;
  }
}

// ---------------- fused LayerNorm over NP bf16 partials (+bias +residual) ----------------
template<int NP, int WRITEB>
__global__ __launch_bounds__(256) void lnp_kernel(const unsigned short* __restrict__ part,
                                                  const float* __restrict__ bias,
                                                  const float* __restrict__ resid,
                                                  const float* __restrict__ gamma,
                                                  const float* __restrict__ beta,
                                                  unsigned short* __restrict__ outb,
                                                  float* __restrict__ outf){
  const int row = blockIdx.x, t = threadIdx.x;
  const size_t base = (size_t)row * 1024 + t * 4;
  const f32x4 rv = *(const f32x4*)(resid + base);
  float s[4];
  #pragma unroll
  for (int i = 0; i < 4; i++) s[i] = bias[t * 4 + i] + rv[i];
  #pragma unroll
  for (int q = 0; q < NP; q++){
    const u16x4 a = *(const u16x4*)(part + (size_t)q * 4194304 + base);
    #pragma unroll
    for (int i = 0; i < 4; i++) s[i] += bf2f(a[i]);
  }
  float sum = (s[0] + s[1]) + (s[2] + s[3]);
  float sq = s[0] * s[0] + s[1] * s[1] + s[2] * s[2] + s[3] * s[3];
  #pragma unroll
  for (int off = 32; off >= 1; off >>= 1){
    sum += __shfl_xor(sum, off);
    sq  += __shfl_xor(sq, off);
  }
  __shared__ float red[8];
  const int lane = t & 63, w = t >> 6;
  if (lane == 0){ red[w] = sum; red[4 + w] = sq; }
  __syncthreads();
  sum = red[0] + red[1] + red[2] + red[3];
  sq  = red[4] + red[5] + red[6] + red[7];
  const float mu = sum * (1.f / 1024.f);
  const float var = sq * (1.f / 1024.f) - mu * mu;
  const float rstd = rsqrtf(var + 1e-5f);
  #pragma unroll
  for (int i = 0; i < 4; i++){
    const int col = t * 4 + i;
    const float ov = (s[i] - mu) * rstd * gamma[col] + beta[col];
    if (WRITEB) outb[base + i] = f2bf(ov);
    outf[base + i] = ov;
  }
}

// ---------------- launcher ----------------
extern "C" void kernel_launch(void* const* d_in, const int* in_sizes, int n_in,
                              void* d_out, int out_size, void* d_ws, size_t ws_size,
                              hipStream_t stream) {
  const float* x   = (const float*)d_in[0];
  const float* Wq  = (const float*)d_in[1];
  const float* bq  = (const float*)d_in[2];
  const float* Wk  = (const float*)d_in[3];
  const float* bk  = (const float*)d_in[4];
  const float* Wv  = (const float*)d_in[5];
  const float* bv  = (const float*)d_in[6];
  const float* Wo  = (const float*)d_in[7];
  const float* bo  = (const float*)d_in[8];
  const float* g1  = (const float*)d_in[9];
  const float* b1  = (const float*)d_in[10];
  const float* Wi  = (const float*)d_in[11];
  const float* bi  = (const float*)d_in[12];
  const float* Wf  = (const float*)d_in[13];
  const float* bfv = (const float*)d_in[14];
  const float* g2  = (const float*)d_in[15];
  const float* b2  = (const float*)d_in[16];
  const int*   am  = (const int*)d_in[17];

  char* ws = (char*)d_ws;
  const size_t MB = 1ull << 20;
  // lifetime-aliased layout (peak 72 MB; +32 MB at [72,104) if available for FF2 split-4):
  unsigned short* qkv    = (unsigned short*)(ws + 0);        // [0,24M)   QKV..attn
  float*          attn_f = (float*)         (ws + 0);        // [0,16M)   LN1..LN2
  unsigned short* attn_b = (unsigned short*)(ws + 16 * MB);  // [16,24M)  LN1..FF1
  unsigned short* fp2    = (unsigned short*)(ws + 16 * MB);  // [16,32M)  FF2 x2 partials..LN2
  unsigned short* xb     = (unsigned short*)(ws + 24 * MB);  // [24,32M)  cast..QKV
  unsigned short* ctx    = (unsigned short*)(ws + 24 * MB);  // [24,32M)  attn..oproj
  unsigned short* wt     = (unsigned short*)(ws + 32 * MB);  // [32,40M)  weight^T (reused)
  float*          bias3  = (float*)         (ws + 40 * MB);  // [40M,+12K) QKV only
  unsigned short* op2    = (unsigned short*)(ws + 40 * MB);  // [40,56M)  oproj x2 partials..LN1
  unsigned short* inter  = (unsigned short*)(ws + 40 * MB);  // [40,72M)  FF1..FF2
  unsigned short* fp4    = (unsigned short*)(ws + 72 * MB);  // [72,104M) FF2 x4 partials (big ws)
  const bool big = ws_size >= 104 * MB;

  // 1. cast x -> bf16
  cast_x_kernel<<<4096, 256, 0, stream>>>(x, xb);
  // 2. W^T for QKV + packed bias
  transpose_cast<<<dim3(32, 32), dim3(32, 8), 0, stream>>>(Wq, wt + 0,            1024, 1024);
  transpose_cast<<<dim3(32, 32), dim3(32, 8), 0, stream>>>(Wk, wt + 1024 * 1024,  1024, 1024);
  transpose_cast<<<dim3(32, 32), dim3(32, 8), 0, stream>>>(Wv, wt + 2048 * 1024,  1024, 1024);
  pack_bias3<<<12, 256, 0, stream>>>(bq, bk, bv, bias3);
  // 3. QKV GEMM -> qkv [4096][3072]
  gemm1b<0><<<dim3(24, 32, 1), 256, 0, stream>>>(xb, wt, bias3, qkv, 4096, 3072, 1024, 1024);
  // 4. fused attention -> ctx [4096][1024]
  attn_kernel<<<dim3(128, 8), 256, 0, stream>>>(qkv, am, ctx);
  // 5. Wo^T ; o-proj split-K=2 -> op2 bf16 partials (512 blocks, NT=8)
  transpose_cast<<<dim3(32, 32), dim3(32, 8), 0, stream>>>(Wo, wt, 1024, 1024);
  gemm1b<3><<<dim3(8, 32, 2), 256, 0, stream>>>(ctx, wt, nullptr, op2, 4096, 1024, 1024, 512);
  // 6. LN1: op2 sum + bo + x -> attn_b bf16, attn_f f32
  lnp_kernel<2, 1><<<4096, 256, 0, stream>>>(op2, bo, x, g1, b1, attn_b, attn_f);
  // 7. Wi^T ; FF1 GEMM (+gelu) -> inter bf16 [4096][4096]  (EXPERIMENT: gemm8w 256² + num_vgpr)
  transpose_cast<<<dim3(128, 32), dim3(32, 8), 0, stream>>>(Wi, wt, 1024, 4096);
  gemm8w<1><<<dim3(16, 16, 1), 512, 0, stream>>>(attn_b, wt, bi, inter, 4096, 4096, 1024, 1024);
  // 8. Wf^T ; FF2 split-K -> partials ; 9. LN2 -> d_out f32
  transpose_cast<<<dim3(32, 128), dim3(32, 8), 0, stream>>>(Wf, wt, 4096, 1024);
  if (big){
    gemm1b<3><<<dim3(8, 32, 4), 256, 0, stream>>>(inter, wt, nullptr, fp4, 4096, 1024, 4096, 1024);
    lnp_kernel<4, 0><<<4096, 256, 0, stream>>>(fp4, bfv, attn_f, g2, b2, nullptr, (float*)d_out);
  } else {
    gemm1b<3><<<dim3(8, 32, 2), 256, 0, stream>>>(inter, wt, nullptr, fp2, 4096, 1024, 4096, 2048);
    lnp_kernel<2, 0><<<4096, 256, 0, stream>>>(fp2, bfv, attn_f, g2, b2, nullptr, (float*)d_out);
  }
}

// Round 16
// 241.150 us; speedup vs baseline: 1.2068x; 1.2068x over previous
//
#include <hip/hip_runtime.h>
#include <hip/hip_bf16.h>

typedef __attribute__((ext_vector_type(8))) short short8;
typedef __attribute__((ext_vector_type(4))) float f32x4;
typedef __attribute__((ext_vector_type(4))) unsigned short u16x4;

// B=8 S=512 H=1024 NH=16 D=64 FF=4096 ; tokens M=4096

__device__ __forceinline__ unsigned short f2bf(float f){
  union { float f; unsigned u; } v; v.f = f;
  return (unsigned short)((v.u + 0x7FFFu + ((v.u >> 16) & 1u)) >> 16);
}
__device__ __forceinline__ float bf2f(unsigned short h){
  union { unsigned u; float f; } v; v.u = ((unsigned)h) << 16; return v.f;
}
// async global->LDS, 16B per lane; lds base must be wave-uniform (HW: base + lane*16)
__device__ __forceinline__ void gll16(const unsigned short* g, unsigned short* l){
  __builtin_amdgcn_global_load_lds((const __attribute__((address_space(1))) unsigned int*)g,
                                   (__attribute__((address_space(3))) unsigned int*)l, 16, 0, 0);
}

// ---------------- prep kernels ----------------
__global__ __launch_bounds__(256) void cast_x_kernel(const float* __restrict__ x,
                                                     unsigned short* __restrict__ xb){
  size_t i = (size_t)blockIdx.x * 256 + threadIdx.x;
  const f32x4 v = *(const f32x4*)(x + i * 4);
  u16x4 o;
  o[0] = f2bf(v[0]); o[1] = f2bf(v[1]); o[2] = f2bf(v[2]); o[3] = f2bf(v[3]);
  *(u16x4*)(xb + i * 4) = o;
}

// src fp32 [R][C] -> dst bf16 [C][R]
__global__ __launch_bounds__(256) void transpose_cast(const float* __restrict__ src,
                                                      unsigned short* __restrict__ dst,
                                                      int R, int C){
  __shared__ float tile[32][33];
  const int tx = threadIdx.x, ty = threadIdx.y;
  const int c0 = blockIdx.x * 32, r0 = blockIdx.y * 32;
  #pragma unroll
  for (int i = ty; i < 32; i += 8)
    tile[i][tx] = src[(size_t)(r0 + i) * C + c0 + tx];
  __syncthreads();
  #pragma unroll
  for (int i = ty; i < 32; i += 8)
    dst[(size_t)(c0 + i) * R + r0 + tx] = f2bf(tile[tx][i]);
}

__global__ void pack_bias3(const float* __restrict__ a, const float* __restrict__ b,
                           const float* __restrict__ c, float* __restrict__ out){
  const int i = blockIdx.x * 256 + threadIdx.x;
  out[i] = (i < 1024) ? a[i] : (i < 2048 ? b[i - 1024] : c[i - 2048]);
}

// ======== gemm1b: 128x128 tile, 4 waves, BK=64 SINGLE buffer, 32KB LDS ========
// SESSION-BEST GEMM (R10-R14 verified): ~675 TF, VGPR 80, 0 bank conflicts, 4 blocks/CU.
// Bracketed from SEVEN directions (8w thin/fat, BK=32 deep-prefetch, dbuf 2blk/CU,
// fat-BN 128x256, 32x32x16 MFMA shape, 256-reg 8w via 4 allocator attributes — all
// refused at 128 VGPR + spill). This is the robust local optimum the toolchain admits.
// Per tile: BAR -> stage(8 gll16) -> vmcnt(0)+BAR -> 16 ds_read + 32 MFMA.
// Swizzle (0-conflict verified): 16B-slot ^= (row&7), both sides; rows span lane&15.
// EMPIRICAL RULE (R2/R6/R13): read patterns whose row spans lane&31 conflict (4.19M);
// rows spanning lane&15 with slot^=(c&7) measure exactly 0 — keep this pattern.
// EPI: 0 = bias->bf16 ; 1 = bias+gelu->bf16 ; 3 = raw->bf16 partial (split-K, no bias)
template<int EPI>
__global__ __launch_bounds__(256) void gemm1b(const unsigned short* __restrict__ A,
                                              const unsigned short* __restrict__ Bt,
                                              const float* __restrict__ bias,
                                              unsigned short* __restrict__ Cout,
                                              int M, int N, int K, int Ksub){
  __shared__ unsigned short smA[128 * 64];
  __shared__ unsigned short smB[128 * 64];
  const int t = threadIdx.x;
  const int lane = t & 63, w = t >> 6;
  const int wr = w >> 1, wc = w & 1;
  const int g = lane >> 4, c = lane & 15;

  // bijective XCD swizzle (m204 form)
  const int gx = gridDim.x;
  const int nwg = gx * gridDim.y;
  int lin = blockIdx.y * gx + blockIdx.x;
  { const int q = nwg >> 3, r = nwg & 7, x = lin & 7, p = lin >> 3;
    lin = (x < r) ? x * (q + 1) + p : r * (q + 1) + (x - r) * q + p; }
  const int bn = lin % gx, bm = lin / gx;

  const size_t Kd = (size_t)K;
  const int k0 = blockIdx.z * Ksub;

  const int srow = t >> 3;                   // 0..31
  const int sslot = (t & 7) ^ (srow & 7);    // inverse-swizzled global slot
  const unsigned short* gA = A + (size_t)(bm * 128 + srow) * Kd + k0 + sslot * 8;
  const unsigned short* gB = Bt + (size_t)(bn * 128 + srow) * Kd + k0 + sslot * 8;

  const int arow = (wr * 64 + c) * 64;
  const int brow = (wc * 64 + c) * 64;
  const int sl0 = (g ^ (c & 7)) * 8;
  const int sl1 = ((g | 4) ^ (c & 7)) * 8;

  f32x4 acc[4][4];
  #pragma unroll
  for (int m = 0; m < 4; m++)
    #pragma unroll
    for (int n = 0; n < 4; n++) acc[m][n] = (f32x4){0.f, 0.f, 0.f, 0.f};
  short8 af[4], bfr[4];

  const int NT = Ksub >> 6;   // K-tiles of 64

#define STAGE1(T) do { \
    const unsigned short* ga_ = gA + (size_t)(T) * 64; \
    const unsigned short* gb_ = gB + (size_t)(T) * 64; \
    gll16(ga_,            &smA[(0  + w * 8) * 64]); \
    gll16(ga_ + 32 * Kd,  &smA[(32 + w * 8) * 64]); \
    gll16(ga_ + 64 * Kd,  &smA[(64 + w * 8) * 64]); \
    gll16(ga_ + 96 * Kd,  &smA[(96 + w * 8) * 64]); \
    gll16(gb_,            &smB[(0  + w * 8) * 64]); \
    gll16(gb_ + 32 * Kd,  &smB[(32 + w * 8) * 64]); \
    gll16(gb_ + 64 * Kd,  &smB[(64 + w * 8) * 64]); \
    gll16(gb_ + 96 * Kd,  &smB[(96 + w * 8) * 64]); } while (0)

  for (int tt = 0; tt < NT; ++tt){
    if (tt) __builtin_amdgcn_s_barrier();     // all waves done reading previous tile
    STAGE1(tt);
    asm volatile("s_waitcnt vmcnt(0)" ::: "memory");
    __builtin_amdgcn_s_barrier();             // tile visible to all waves
    #pragma unroll
    for (int m = 0; m < 4; m++) af[m]  = *(const short8*)&smA[arow + m * 1024 + sl0];
    #pragma unroll
    for (int n = 0; n < 4; n++) bfr[n] = *(const short8*)&smB[brow + n * 1024 + sl0];
    __builtin_amdgcn_s_setprio(1);
    #pragma unroll
    for (int m = 0; m < 4; m++)
      #pragma unroll
      for (int n = 0; n < 4; n++)
        acc[m][n] = __builtin_amdgcn_mfma_f32_16x16x32_bf16(af[m], bfr[n], acc[m][n], 0, 0, 0);
    #pragma unroll
    for (int m = 0; m < 4; m++) af[m]  = *(const short8*)&smA[arow + m * 1024 + sl1];
    #pragma unroll
    for (int n = 0; n < 4; n++) bfr[n] = *(const short8*)&smB[brow + n * 1024 + sl1];
    #pragma unroll
    for (int m = 0; m < 4; m++)
      #pragma unroll
      for (int n = 0; n < 4; n++)
        acc[m][n] = __builtin_amdgcn_mfma_f32_16x16x32_bf16(af[m], bfr[n], acc[m][n], 0, 0, 0);
    __builtin_amdgcn_s_setprio(0);
  }
#undef STAGE1

  // epilogue: C[row0+m*16+4g+r][col0+n*16+c]
  const int row0 = bm * 128 + wr * 64;
  const int col0 = bn * 128 + wc * 64;
  unsigned short* outp = Cout + (EPI == 3 ? (size_t)blockIdx.z * ((size_t)M * N) : 0);
  #pragma unroll
  for (int n = 0; n < 4; n++){
    const int col = col0 + n * 16 + c;
    const float bs = (EPI == 3) ? 0.f : bias[col];
    #pragma unroll
    for (int m = 0; m < 4; m++){
      const int row = row0 + m * 16 + g * 4;
      #pragma unroll
      for (int r = 0; r < 4; r++){
        float v = acc[m][n][r] + bs;
        if (EPI == 1){
          // gelu(x) = x * sigmoid(2*sqrt(2/pi)*(x + 0.044715 x^3))  (== tanh form)
          const float u2 = 1.5957691216057308f * (v + 0.044715f * v * v * v);
          v = v * __fdividef(1.f, 1.f + __expf(-u2));
        }
        outp[(size_t)(row + r) * N + col] = f2bf(v);
      }
    }
  }
}

// ---------------- fused attention (R8: 2 blocks/CU via chunked K/V staging) ----------------
// 256 threads (4 waves, 64 q-rows), K/V staged in 256-key chunks -> LDS 72KB -> 2
// blocks/CU. All 512 scores stay in registers; softmax identical; staging chunked behind
// full barriers. grid (128 heads, 8 q-tiles) = 1024 blocks = 2 rounds.
__global__ __launch_bounds__(256) void attn_kernel(const unsigned short* __restrict__ qkv,
                                                   const int* __restrict__ mask,
                                                   unsigned short* __restrict__ ctx){
  __shared__ unsigned short k_sm[256 * 72];    // [key-chunk][d], pad 64->72
  __shared__ unsigned short vt_sm[64 * 272];   // [d][key-chunk], pad 256->272
  __shared__ float madd[512];
  const int t = threadIdx.x;
  const int hb = blockIdx.x;
  const int qt = blockIdx.y;                   // 0..7
  const int b = hb >> 4, h = hb & 15;
  const size_t headq = (size_t)b * 512 * 3072 + h * 64;

#define STAGE_K(K0) do { \
    _Pragma("unroll") \
    for (int p = 0; p < 8; p++){ \
      const int row = p * 32 + (t >> 3); \
      const int col = (t & 7) * 8; \
      const short8 v = *(const short8*)(qkv + headq + (size_t)((K0) + row) * 3072 + 1024 + col); \
      *(short8*)(k_sm + row * 72 + col) = v; \
    } } while (0)
#define STAGE_VT(K0) do { \
    const unsigned short* vp_ = qkv + headq + (size_t)((K0) + t) * 3072 + 2048; \
    short8 vv_[8]; \
    _Pragma("unroll") \
    for (int j = 0; j < 8; j++) vv_[j] = *(const short8*)(vp_ + j * 8); \
    _Pragma("unroll") \
    for (int j = 0; j < 8; j++) \
      _Pragma("unroll") \
      for (int e = 0; e < 8; e++) \
        vt_sm[(j * 8 + e) * 272 + t] = (unsigned short)vv_[j][e]; \
  } while (0)

  STAGE_K(0);
  STAGE_VT(0);
  madd[t]       = (1.f - (float)mask[b * 512 + t]) * -10000.f;
  madd[256 + t] = (1.f - (float)mask[b * 512 + 256 + t]) * -10000.f;
  __syncthreads();

  const int w = t >> 6, lane = t & 63, g = lane >> 4, c = lane & 15;
  const int qrow = qt * 64 + w * 16 + c;
  const unsigned short* qp = qkv + (size_t)(b * 512 + qrow) * 3072 + h * 64;
  const short8 qf0 = *(const short8*)(qp + 8 * g);
  const short8 qf1 = *(const short8*)(qp + 32 + 8 * g);

  f32x4 p[32];
  // QK^T chunk 0 (keys 0..255)
  #pragma unroll
  for (int mt = 0; mt < 16; mt++){
    const short8 a0 = *(const short8*)(k_sm + (mt * 16 + c) * 72 + 8 * g);
    const short8 a1 = *(const short8*)(k_sm + (mt * 16 + c) * 72 + 32 + 8 * g);
    f32x4 z = (f32x4){0.f, 0.f, 0.f, 0.f};
    z = __builtin_amdgcn_mfma_f32_16x16x32_bf16(a0, qf0, z, 0, 0, 0);
    z = __builtin_amdgcn_mfma_f32_16x16x32_bf16(a1, qf1, z, 0, 0, 0);
    p[mt] = z;
  }
  __syncthreads();           // all waves done reading k_sm chunk 0
  STAGE_K(256);
  __syncthreads();
  // QK^T chunk 1 (keys 256..511)
  #pragma unroll
  for (int mt = 16; mt < 32; mt++){
    const short8 a0 = *(const short8*)(k_sm + ((mt - 16) * 16 + c) * 72 + 8 * g);
    const short8 a1 = *(const short8*)(k_sm + ((mt - 16) * 16 + c) * 72 + 32 + 8 * g);
    f32x4 z = (f32x4){0.f, 0.f, 0.f, 0.f};
    z = __builtin_amdgcn_mfma_f32_16x16x32_bf16(a0, qf0, z, 0, 0, 0);
    z = __builtin_amdgcn_mfma_f32_16x16x32_bf16(a1, qf1, z, 0, 0, 0);
    p[mt] = z;
  }

  float mx = -1e30f;
  #pragma unroll
  for (int mt = 0; mt < 32; mt++){
    #pragma unroll
    for (int r = 0; r < 4; r++){
      const float sv = p[mt][r] * 0.125f + madd[mt * 16 + 4 * g + r];
      p[mt][r] = sv;
      mx = fmaxf(mx, sv);
    }
  }
  mx = fmaxf(mx, __shfl_xor(mx, 16));
  mx = fmaxf(mx, __shfl_xor(mx, 32));

  float sum = 0.f;
  unsigned pd[32][2];
  #pragma unroll
  for (int mt = 0; mt < 32; mt++){
    const float e0 = __expf(p[mt][0] - mx);
    const float e1 = __expf(p[mt][1] - mx);
    const float e2 = __expf(p[mt][2] - mx);
    const float e3 = __expf(p[mt][3] - mx);
    sum += (e0 + e1) + (e2 + e3);
    pd[mt][0] = (unsigned)f2bf(e0) | ((unsigned)f2bf(e1) << 16);
    pd[mt][1] = (unsigned)f2bf(e2) | ((unsigned)f2bf(e3) << 16);
  }
  sum += __shfl_xor(sum, 16);
  sum += __shfl_xor(sum, 32);
  const float rsum = 1.f / sum;

  f32x4 o[4];
  #pragma unroll
  for (int dt = 0; dt < 4; dt++) o[dt] = (f32x4){0.f, 0.f, 0.f, 0.f};
  const int sA = (2 * (g & 1)) * 16 + c;
  const int sB = sA + 16;
  const int hi = g >> 1;

#define PVBLK(KT0) \
  _Pragma("unroll") \
  for (int kk = 0; kk < 8; kk++){ \
    const int kt = (KT0) + kk; \
    const unsigned w0a = (unsigned)__shfl((int)pd[2 * kt][0], sA); \
    const unsigned w1a = (unsigned)__shfl((int)pd[2 * kt][1], sA); \
    const unsigned w2a = (unsigned)__shfl((int)pd[2 * kt][0], sB); \
    const unsigned w3a = (unsigned)__shfl((int)pd[2 * kt][1], sB); \
    const unsigned w0b = (unsigned)__shfl((int)pd[2 * kt + 1][0], sA); \
    const unsigned w1b = (unsigned)__shfl((int)pd[2 * kt + 1][1], sA); \
    const unsigned w2b = (unsigned)__shfl((int)pd[2 * kt + 1][0], sB); \
    const unsigned w3b = (unsigned)__shfl((int)pd[2 * kt + 1][1], sB); \
    union { unsigned u[4]; short8 s; } bu; \
    bu.u[0] = hi ? w0b : w0a; \
    bu.u[1] = hi ? w1b : w1a; \
    bu.u[2] = hi ? w2b : w2a; \
    bu.u[3] = hi ? w3b : w3a; \
    _Pragma("unroll") \
    for (int dt = 0; dt < 4; dt++){ \
      const short8 av = *(const short8*)(vt_sm + (dt * 16 + c) * 272 + kk * 32 + 8 * g); \
      o[dt] = __builtin_amdgcn_mfma_f32_16x16x32_bf16(av, bu.s, o[dt], 0, 0, 0); \
    } \
  }

  PVBLK(0);                  // keys 0..255 from vt chunk 0
  __syncthreads();           // all waves done reading vt chunk 0
  STAGE_VT(256);
  __syncthreads();
  PVBLK(8);                  // keys 256..511 from vt chunk 1

#undef PVBLK
#undef STAGE_K
#undef STAGE_VT

  #pragma unroll
  for (int dt = 0; dt < 4; dt++){
    u16x4 st;
    #pragma unroll
    for (int r = 0; r < 4; r++) st[r] = f2bf(o[dt][r] * rsum);
    *(u16x4*)(ctx + (size_t)(b * 512 + qrow) * 1024 + h * 64 + dt * 16 + 4 * g) = st;
  }
}

// ---------------- fused LayerNorm over NP bf16 partials (+bias +residual) ----------------
template<int NP, int WRITEB>
__global__ __launch_bounds__(256) void lnp_kernel(const unsigned short* __restrict__ part,
                                                  const float* __restrict__ bias,
                                                  const float* __restrict__ resid,
                                                  const float* __restrict__ gamma,
                                                  const float* __restrict__ beta,
                                                  unsigned short* __restrict__ outb,
                                                  float* __restrict__ outf){
  const int row = blockIdx.x, t = threadIdx.x;
  const size_t base = (size_t)row * 1024 + t * 4;
  const f32x4 rv = *(const f32x4*)(resid + base);
  float s[4];
  #pragma unroll
  for (int i = 0; i < 4; i++) s[i] = bias[t * 4 + i] + rv[i];
  #pragma unroll
  for (int q = 0; q < NP; q++){
    const u16x4 a = *(const u16x4*)(part + (size_t)q * 4194304 + base);
    #pragma unroll
    for (int i = 0; i < 4; i++) s[i] += bf2f(a[i]);
  }
  float sum = (s[0] + s[1]) + (s[2] + s[3]);
  float sq = s[0] * s[0] + s[1] * s[1] + s[2] * s[2] + s[3] * s[3];
  #pragma unroll
  for (int off = 32; off >= 1; off >>= 1){
    sum += __shfl_xor(sum, off);
    sq  += __shfl_xor(sq, off);
  }
  __shared__ float red[8];
  const int lane = t & 63, w = t >> 6;
  if (lane == 0){ red[w] = sum; red[4 + w] = sq; }
  __syncthreads();
  sum = red[0] + red[1] + red[2] + red[3];
  sq  = red[4] + red[5] + red[6] + red[7];
  const float mu = sum * (1.f / 1024.f);
  const float var = sq * (1.f / 1024.f) - mu * mu;
  const float rstd = rsqrtf(var + 1e-5f);
  #pragma unroll
  for (int i = 0; i < 4; i++){
    const int col = t * 4 + i;
    const float ov = (s[i] - mu) * rstd * gamma[col] + beta[col];
    if (WRITEB) outb[base + i] = f2bf(ov);
    outf[base + i] = ov;
  }
}

// ---------------- launcher ----------------
extern "C" void kernel_launch(void* const* d_in, const int* in_sizes, int n_in,
                              void* d_out, int out_size, void* d_ws, size_t ws_size,
                              hipStream_t stream) {
  const float* x   = (const float*)d_in[0];
  const float* Wq  = (const float*)d_in[1];
  const float* bq  = (const float*)d_in[2];
  const float* Wk  = (const float*)d_in[3];
  const float* bk  = (const float*)d_in[4];
  const float* Wv  = (const float*)d_in[5];
  const float* bv  = (const float*)d_in[6];
  const float* Wo  = (const float*)d_in[7];
  const float* bo  = (const float*)d_in[8];
  const float* g1  = (const float*)d_in[9];
  const float* b1  = (const float*)d_in[10];
  const float* Wi  = (const float*)d_in[11];
  const float* bi  = (const float*)d_in[12];
  const float* Wf  = (const float*)d_in[13];
  const float* bfv = (const float*)d_in[14];
  const float* g2  = (const float*)d_in[15];
  const float* b2  = (const float*)d_in[16];
  const int*   am  = (const int*)d_in[17];

  char* ws = (char*)d_ws;
  const size_t MB = 1ull << 20;
  // lifetime-aliased layout (peak 72 MB; +32 MB at [72,104) if available for FF2 split-4):
  unsigned short* qkv    = (unsigned short*)(ws + 0);        // [0,24M)   QKV..attn
  float*          attn_f = (float*)         (ws + 0);        // [0,16M)   LN1..LN2
  unsigned short* attn_b = (unsigned short*)(ws + 16 * MB);  // [16,24M)  LN1..FF1
  unsigned short* fp2    = (unsigned short*)(ws + 16 * MB);  // [16,32M)  FF2 x2 partials..LN2
  unsigned short* xb     = (unsigned short*)(ws + 24 * MB);  // [24,32M)  cast..QKV
  unsigned short* ctx    = (unsigned short*)(ws + 24 * MB);  // [24,32M)  attn..oproj
  unsigned short* wt     = (unsigned short*)(ws + 32 * MB);  // [32,40M)  weight^T (reused)
  float*          bias3  = (float*)         (ws + 40 * MB);  // [40M,+12K) QKV only
  unsigned short* op2    = (unsigned short*)(ws + 40 * MB);  // [40,56M)  oproj x2 partials..LN1
  unsigned short* inter  = (unsigned short*)(ws + 40 * MB);  // [40,72M)  FF1..FF2
  unsigned short* fp4    = (unsigned short*)(ws + 72 * MB);  // [72,104M) FF2 x4 partials (big ws)
  const bool big = ws_size >= 104 * MB;

  // 1. cast x -> bf16
  cast_x_kernel<<<4096, 256, 0, stream>>>(x, xb);
  // 2. W^T for QKV + packed bias
  transpose_cast<<<dim3(32, 32), dim3(32, 8), 0, stream>>>(Wq, wt + 0,            1024, 1024);
  transpose_cast<<<dim3(32, 32), dim3(32, 8), 0, stream>>>(Wk, wt + 1024 * 1024,  1024, 1024);
  transpose_cast<<<dim3(32, 32), dim3(32, 8), 0, stream>>>(Wv, wt + 2048 * 1024,  1024, 1024);
  pack_bias3<<<12, 256, 0, stream>>>(bq, bk, bv, bias3);
  // 3. QKV GEMM -> qkv [4096][3072]
  gemm1b<0><<<dim3(24, 32, 1), 256, 0, stream>>>(xb, wt, bias3, qkv, 4096, 3072, 1024, 1024);
  // 4. fused attention -> ctx [4096][1024]
  attn_kernel<<<dim3(128, 8), 256, 0, stream>>>(qkv, am, ctx);
  // 5. Wo^T ; o-proj split-K=2 -> op2 bf16 partials (512 blocks, NT=8)
  transpose_cast<<<dim3(32, 32), dim3(32, 8), 0, stream>>>(Wo, wt, 1024, 1024);
  gemm1b<3><<<dim3(8, 32, 2), 256, 0, stream>>>(ctx, wt, nullptr, op2, 4096, 1024, 1024, 512);
  // 6. LN1: op2 sum + bo + x -> attn_b bf16, attn_f f32
  lnp_kernel<2, 1><<<4096, 256, 0, stream>>>(op2, bo, x, g1, b1, attn_b, attn_f);
  // 7. Wi^T ; FF1 GEMM (+gelu) -> inter bf16 [4096][4096]
  transpose_cast<<<dim3(128, 32), dim3(32, 8), 0, stream>>>(Wi, wt, 1024, 4096);
  gemm1b<1><<<dim3(32, 32, 1), 256, 0, stream>>>(attn_b, wt, bi, inter, 4096, 4096, 1024, 1024);
  // 8. Wf^T ; FF2 split-K -> partials ; 9. LN2 -> d_out f32
  transpose_cast<<<dim3(32, 128), dim3(32, 8), 0, stream>>>(Wf, wt, 4096, 1024);
  if (big){
    gemm1b<3><<<dim3(8, 32, 4), 256, 0, stream>>>(inter, wt, nullptr, fp4, 4096, 1024, 4096, 1024);
    lnp_kernel<4, 0><<<4096, 256, 0, stream>>>(fp4, bfv, attn_f, g2, b2, nullptr, (float*)d_out);
  } else {
    gemm1b<3><<<dim3(8, 32, 2), 256, 0, stream>>>(inter, wt, nullptr, fp2, 4096, 1024, 4096, 2048);
    lnp_kernel<2, 0><<<4096, 256, 0, stream>>>(fp2, bfv, attn_f, g2, b2, nullptr, (float*)d_out);
  }
}